// Round 1
// baseline (1430.223 us; speedup 1.0000x reference)
//
#include <hip/hip_runtime.h>
#include <hip/hip_bf16.h>
#include <math.h>

// ---------------------------------------------------------------------------
// BiFormerAttention: B=4, N=2048, C=768, H=12, hd=64, keep=1024
// Layout of qkv buffer: [B][N][3][H][hd] fp32 (natural GEMM output, row len 2304)
// ---------------------------------------------------------------------------

#define B_  4
#define N_  2048
#define C_  768
#define H_  12
#define HD_ 64
#define KEEP_ 1024
#define BH_ (B_ * H_)

// ---------------- fp32 SGEMM: 64x64 tile, BK=16, 256 thr, 4x4/thread --------
template <bool EPILOGUE>
__global__ __launch_bounds__(256) void sgemm64(
    const float* __restrict__ A, const float* __restrict__ Bm,
    float* __restrict__ C, int M, int N, int K, const float* __restrict__ bias)
{
    __shared__ __align__(16) float As[16][72];  // As[kk][row]  (transposed A tile)
    __shared__ __align__(16) float Bs[16][72];  // Bs[kk][col]

    const int bx = blockIdx.x;   // N tile
    const int by = blockIdx.y;   // M tile
    const int tid = threadIdx.x;
    const int tx = tid & 15;     // col group
    const int ty = tid >> 4;     // row group
    const int row0 = by * 64, col0 = bx * 64;

    float acc[4][4];
#pragma unroll
    for (int i = 0; i < 4; ++i)
#pragma unroll
        for (int j = 0; j < 4; ++j) acc[i][j] = 0.f;

    for (int k0 = 0; k0 < K; k0 += 16) {
        // A tile: 64 rows x 16 cols -> store transposed
        {
            int r = tid >> 2, c4 = (tid & 3) << 2;
            float4 av = *reinterpret_cast<const float4*>(&A[(size_t)(row0 + r) * K + k0 + c4]);
            As[c4 + 0][r] = av.x;
            As[c4 + 1][r] = av.y;
            As[c4 + 2][r] = av.z;
            As[c4 + 3][r] = av.w;
        }
        // B tile: 16 rows x 64 cols
        {
            int r = tid >> 4, c4 = (tid & 15) << 2;
            float4 bv = *reinterpret_cast<const float4*>(&Bm[(size_t)(k0 + r) * N + col0 + c4]);
            *reinterpret_cast<float4*>(&Bs[r][c4]) = bv;
        }
        __syncthreads();
#pragma unroll
        for (int kk = 0; kk < 16; ++kk) {
            float4 a4 = *reinterpret_cast<const float4*>(&As[kk][ty << 2]);
            float4 b4 = *reinterpret_cast<const float4*>(&Bs[kk][tx << 2]);
            float a[4] = {a4.x, a4.y, a4.z, a4.w};
            float b[4] = {b4.x, b4.y, b4.z, b4.w};
#pragma unroll
            for (int i = 0; i < 4; ++i)
#pragma unroll
                for (int j = 0; j < 4; ++j) acc[i][j] += a[i] * b[j];
        }
        __syncthreads();
    }

#pragma unroll
    for (int i = 0; i < 4; ++i) {
        int r = row0 + (ty << 2) + i;
        int c = col0 + (tx << 2);
        float4 v;
        v.x = acc[i][0]; v.y = acc[i][1]; v.z = acc[i][2]; v.w = acc[i][3];
        if (EPILOGUE) {
            v.x = fminf(fmaxf(v.x + bias[c + 0], -10.f), 10.f);
            v.y = fminf(fmaxf(v.y + bias[c + 1], -10.f), 10.f);
            v.z = fminf(fmaxf(v.z + bias[c + 2], -10.f), 10.f);
            v.w = fminf(fmaxf(v.w + bias[c + 3], -10.f), 10.f);
        }
        *reinterpret_cast<float4*>(&C[(size_t)r * N + c]) = v;
    }
}

// ---------------- scores = sum(q^2) per (b,h,n) ------------------------------
__global__ __launch_bounds__(256) void score_kernel(
    const float* __restrict__ qkv, float* __restrict__ scores)
{
    int w = blockIdx.x * 4 + (threadIdx.x >> 6);   // 0 .. BH_*N_-1
    int lane = threadIdx.x & 63;
    int bh = w >> 11;          // w / N_
    int n = w & (N_ - 1);
    int b = bh / H_, h = bh % H_;
    float q = qkv[((size_t)b * N_ + n) * (3 * C_) + (size_t)h * HD_ + lane];
    float ss = q * q;
#pragma unroll
    for (int off = 32; off; off >>= 1) ss += __shfl_xor(ss, off);
    if (lane == 0) scores[(size_t)bh * N_ + n] = ss;
}

// ---------------- top-1024 of 2048 per (b,h): bitonic sort ------------------
__global__ __launch_bounds__(1024) void topk_kernel(
    const float* __restrict__ scores, int* __restrict__ keepidx)
{
    __shared__ unsigned long long keys[N_];
    const int bh = blockIdx.x;
    const int tid = threadIdx.x;
    const float* sc = scores + (size_t)bh * N_;
    for (int i = tid; i < N_; i += 1024) {
        unsigned fb = __float_as_uint(sc[i]);  // scores >= 0: bits monotone
        keys[i] = ((unsigned long long)fb << 32) | (unsigned)(N_ - 1 - i);
    }
    __syncthreads();
    for (int k = 2; k <= N_; k <<= 1) {
        for (int j = k >> 1; j > 0; j >>= 1) {
            for (int i = tid; i < N_; i += 1024) {
                int ixj = i ^ j;
                if (ixj > i) {
                    unsigned long long a = keys[i], b = keys[ixj];
                    bool desc = ((i & k) == 0);
                    if (desc ? (a < b) : (a > b)) { keys[i] = b; keys[ixj] = a; }
                }
            }
            __syncthreads();
        }
    }
    if (tid < KEEP_) {
        keepidx[(size_t)bh * KEEP_ + tid] = (N_ - 1) - (int)(keys[tid] & 0xffffffffu);
    }
}

// ---------------- gather k_sel, v_sel ---------------------------------------
__global__ __launch_bounds__(256) void gather_kernel(
    const float* __restrict__ qkv, const int* __restrict__ keepidx,
    float* __restrict__ k_sel, float* __restrict__ v_sel)
{
    int w = blockIdx.x * 4 + (threadIdx.x >> 6);   // 0 .. BH_*KEEP_-1
    int lane = threadIdx.x & 63;
    int bh = w >> 10;          // w / KEEP_
    int i = w & (KEEP_ - 1);
    int b = bh / H_, h = bh % H_;
    int n = keepidx[(size_t)bh * KEEP_ + i];
    size_t base = ((size_t)b * N_ + n) * (3 * C_) + (size_t)h * HD_ + lane;
    size_t dst = ((size_t)bh * KEEP_ + i) * HD_ + lane;
    k_sel[dst] = qkv[base + C_];       // k chunk
    v_sel[dst] = qkv[base + 2 * C_];   // v chunk
}

// ---------------- flash attention over selected keys ------------------------
// block: (bh, 32 q-rows). 4 waves x 8 rows. K-tiles of 64.
__global__ __launch_bounds__(256) void attn_kernel(
    const float* __restrict__ qkv, const float* __restrict__ k_sel,
    const float* __restrict__ v_sel, float* __restrict__ attn_out)
{
    const int bid = blockIdx.x;
    const int bh = bid >> 6;        // /64
    const int qt = bid & 63;
    const int b = bh / H_, h = bh % H_;
    const int tid = threadIdx.x;
    const int wave = tid >> 6;
    const int lane = tid & 63;

    __shared__ float kT[64][65];        // kT[d][j]
    __shared__ float vS[64][64];        // vS[j][d]
    __shared__ float qS[32][64];        // qS[r][d]
    __shared__ float pS[4][8][64];      // per-wave p tile

    // load q rows (8 per wave)
    const size_t qbase = ((size_t)b * N_) * (3 * C_) + (size_t)h * HD_;
#pragma unroll
    for (int r = 0; r < 8; ++r) {
        int n = qt * 32 + wave * 8 + r;
        qS[wave * 8 + r][lane] = qkv[qbase + (size_t)n * (3 * C_) + lane];
    }

    float outv[8], m[8], s[8];
#pragma unroll
    for (int r = 0; r < 8; ++r) { outv[r] = 0.f; m[r] = -1e30f; s[r] = 0.f; }

    const float scale = 0.125f;  // 64^-0.5
    const float* kbh = k_sel + (size_t)bh * KEEP_ * HD_;
    const float* vbh = v_sel + (size_t)bh * KEEP_ * HD_;

    for (int t = 0; t < KEEP_ / 64; ++t) {
        __syncthreads();   // previous tile fully consumed
        // cooperative stage: each wave 16 key rows
#pragma unroll
        for (int jr = 0; jr < 16; ++jr) {
            int j = wave * 16 + jr;
            size_t src = ((size_t)t * 64 + j) * HD_ + lane;
            kT[lane][j] = kbh[src];
            vS[j][lane] = vbh[src];
        }
        __syncthreads();

        // ---- QK^T: lane = key j, rows r of this wave ----
        float l[8];
#pragma unroll
        for (int r = 0; r < 8; ++r) l[r] = 0.f;
        for (int d = 0; d < 64; ++d) {
            float kv = kT[d][lane];
#pragma unroll
            for (int r = 0; r < 8; ++r) l[r] += qS[wave * 8 + r][d] * kv;
        }
        // ---- online softmax ----
#pragma unroll
        for (int r = 0; r < 8; ++r) {
            float lv = l[r] * scale;
            lv = fminf(fmaxf(lv, -50.f), 50.f);
            float mx = lv;
#pragma unroll
            for (int off = 32; off; off >>= 1) mx = fmaxf(mx, __shfl_xor(mx, off));
            float mnew = fmaxf(m[r], mx);
            float c = __expf(m[r] - mnew);
            float p = __expf(lv - mnew);
            float ps = p;
#pragma unroll
            for (int off = 32; off; off >>= 1) ps += __shfl_xor(ps, off);
            s[r] = s[r] * c + ps;
            m[r] = mnew;
            outv[r] *= c;
            pS[wave][r][lane] = p;
        }
        __syncthreads();   // make pS visible (also keeps waves in step)

        // ---- PV: lane = dim d ----
        for (int j2 = 0; j2 < 64; ++j2) {
            float vv = vS[j2][lane];
#pragma unroll
            for (int r = 0; r < 8; ++r) outv[r] += pS[wave][r][j2] * vv;
        }
    }

    // write attn_out[b][n][h][d]
#pragma unroll
    for (int r = 0; r < 8; ++r) {
        int n = qt * 32 + wave * 8 + r;
        attn_out[((size_t)b * N_ + n) * C_ + (size_t)h * HD_ + lane] = outv[r] / s[r];
    }
}

// ---------------------------------------------------------------------------
extern "C" void kernel_launch(void* const* d_in, const int* in_sizes, int n_in,
                              void* d_out, int out_size, void* d_ws, size_t ws_size,
                              hipStream_t stream)
{
    const float* x      = (const float*)d_in[0];
    const float* w_qkv  = (const float*)d_in[1];
    const float* w_proj = (const float*)d_in[2];
    const float* b_proj = (const float*)d_in[3];
    float* out = (float*)d_out;

    float* qkv     = (float*)d_ws;                       // 8192*2304
    float* scores  = qkv + (size_t)B_ * N_ * 3 * C_;     // 98304
    int*   keepidx = (int*)(scores + (size_t)BH_ * N_);  // 49152
    float* k_sel   = (float*)(keepidx + (size_t)BH_ * KEEP_);
    float* v_sel   = k_sel + (size_t)BH_ * KEEP_ * HD_;
    float* attn_o  = v_sel + (size_t)BH_ * KEEP_ * HD_;  // 8192*768

    // 1) qkv = x @ w_qkv    [8192 x 2304]
    {
        dim3 grid((3 * C_) / 64, (B_ * N_) / 64);
        sgemm64<false><<<grid, 256, 0, stream>>>(x, w_qkv, qkv, B_ * N_, 3 * C_, C_, nullptr);
    }
    // 2) scores
    score_kernel<<<(BH_ * N_) / 4, 256, 0, stream>>>(qkv, scores);
    // 3) top-k
    topk_kernel<<<BH_, 1024, 0, stream>>>(scores, keepidx);
    // 4) gather
    gather_kernel<<<(BH_ * KEEP_) / 4, 256, 0, stream>>>(qkv, keepidx, k_sel, v_sel);
    // 5) attention
    attn_kernel<<<BH_ * (N_ / 32), 256, 0, stream>>>(qkv, k_sel, v_sel, attn_o);
    // 6) out = clip(attn_o @ w_proj + b, -10, 10)
    {
        dim3 grid(C_ / 64, (B_ * N_) / 64);
        sgemm64<true><<<grid, 256, 0, stream>>>(attn_o, w_proj, out, B_ * N_, C_, C_, b_proj);
    }
}

// Round 2
// 855.968 us; speedup vs baseline: 1.6709x; 1.6709x over previous
//
#include <hip/hip_runtime.h>
#include <hip/hip_bf16.h>
#include <math.h>

// ---------------------------------------------------------------------------
// BiFormerAttention: B=4, N=2048, C=768, H=12, hd=64, keep=1024
// qkv buffer: [B][N][3][H][hd] fp32 (row len 2304). Attention runs on MFMA
// bf16 with 3-product Markidis split (hi*hi + hi*lo + lo*hi).
// ---------------------------------------------------------------------------

#define B_  4
#define N_  2048
#define C_  768
#define H_  12
#define HD_ 64
#define KEEP_ 1024
#define BH_ (B_ * H_)

typedef __attribute__((ext_vector_type(8))) short short8v;   // 8 bf16 (4 VGPRs)
typedef __attribute__((ext_vector_type(4))) float f32x4;     // MFMA C/D frag

__device__ inline unsigned short f2bf(float f) {             // RNE f32->bf16
    unsigned u = __float_as_uint(f);
    unsigned r = (u + 0x7fffu + ((u >> 16) & 1u)) >> 16;
    return (unsigned short)r;
}
__device__ inline float bf2f(unsigned short h) {
    return __uint_as_float(((unsigned)h) << 16);
}

// ---------------- fp32 SGEMM: 64x64 tile, BK=16, 256 thr, 4x4/thread --------
template <bool EPILOGUE>
__global__ __launch_bounds__(256) void sgemm64(
    const float* __restrict__ A, const float* __restrict__ Bm,
    float* __restrict__ C, int M, int N, int K, const float* __restrict__ bias)
{
    __shared__ __align__(16) float As[16][72];
    __shared__ __align__(16) float Bs[16][72];

    const int bx = blockIdx.x;
    const int by = blockIdx.y;
    const int tid = threadIdx.x;
    const int tx = tid & 15;
    const int ty = tid >> 4;
    const int row0 = by * 64, col0 = bx * 64;

    float acc[4][4];
#pragma unroll
    for (int i = 0; i < 4; ++i)
#pragma unroll
        for (int j = 0; j < 4; ++j) acc[i][j] = 0.f;

    for (int k0 = 0; k0 < K; k0 += 16) {
        {
            int r = tid >> 2, c4 = (tid & 3) << 2;
            float4 av = *reinterpret_cast<const float4*>(&A[(size_t)(row0 + r) * K + k0 + c4]);
            As[c4 + 0][r] = av.x;
            As[c4 + 1][r] = av.y;
            As[c4 + 2][r] = av.z;
            As[c4 + 3][r] = av.w;
        }
        {
            int r = tid >> 4, c4 = (tid & 15) << 2;
            float4 bv = *reinterpret_cast<const float4*>(&Bm[(size_t)(k0 + r) * N + col0 + c4]);
            *reinterpret_cast<float4*>(&Bs[r][c4]) = bv;
        }
        __syncthreads();
#pragma unroll
        for (int kk = 0; kk < 16; ++kk) {
            float4 a4 = *reinterpret_cast<const float4*>(&As[kk][ty << 2]);
            float4 b4 = *reinterpret_cast<const float4*>(&Bs[kk][tx << 2]);
            float a[4] = {a4.x, a4.y, a4.z, a4.w};
            float b[4] = {b4.x, b4.y, b4.z, b4.w};
#pragma unroll
            for (int i = 0; i < 4; ++i)
#pragma unroll
                for (int j = 0; j < 4; ++j) acc[i][j] += a[i] * b[j];
        }
        __syncthreads();
    }

#pragma unroll
    for (int i = 0; i < 4; ++i) {
        int r = row0 + (ty << 2) + i;
        int c = col0 + (tx << 2);
        float4 v;
        v.x = acc[i][0]; v.y = acc[i][1]; v.z = acc[i][2]; v.w = acc[i][3];
        if (EPILOGUE) {
            v.x = fminf(fmaxf(v.x + bias[c + 0], -10.f), 10.f);
            v.y = fminf(fmaxf(v.y + bias[c + 1], -10.f), 10.f);
            v.z = fminf(fmaxf(v.z + bias[c + 2], -10.f), 10.f);
            v.w = fminf(fmaxf(v.w + bias[c + 3], -10.f), 10.f);
        }
        *reinterpret_cast<float4*>(&C[(size_t)r * N + c]) = v;
    }
}

// ---------------- scores = sum(q^2); also emit q hi/lo bf16 -----------------
__global__ __launch_bounds__(256) void score_kernel(
    const float* __restrict__ qkv, float* __restrict__ scores,
    unsigned short* __restrict__ q_hi, unsigned short* __restrict__ q_lo)
{
    int w = blockIdx.x * 4 + (threadIdx.x >> 6);
    int lane = threadIdx.x & 63;
    int bh = w >> 11;
    int n = w & (N_ - 1);
    int b = bh / H_, h = bh % H_;
    float q = qkv[((size_t)b * N_ + n) * (3 * C_) + (size_t)h * HD_ + lane];
    unsigned short qh = f2bf(q);
    size_t qo = ((size_t)bh * N_ + n) * HD_ + lane;
    q_hi[qo] = qh;
    q_lo[qo] = f2bf(q - bf2f(qh));
    float ss = q * q;
#pragma unroll
    for (int off = 32; off; off >>= 1) ss += __shfl_xor(ss, off);
    if (lane == 0) scores[(size_t)bh * N_ + n] = ss;
}

// ---------------- top-1024 of 2048 per (b,h): bitonic sort ------------------
__global__ __launch_bounds__(1024) void topk_kernel(
    const float* __restrict__ scores, int* __restrict__ keepidx)
{
    __shared__ unsigned long long keys[N_];
    const int bh = blockIdx.x;
    const int tid = threadIdx.x;
    const float* sc = scores + (size_t)bh * N_;
    for (int i = tid; i < N_; i += 1024) {
        unsigned fb = __float_as_uint(sc[i]);
        keys[i] = ((unsigned long long)fb << 32) | (unsigned)(N_ - 1 - i);
    }
    __syncthreads();
    for (int k = 2; k <= N_; k <<= 1) {
        for (int j = k >> 1; j > 0; j >>= 1) {
            for (int i = tid; i < N_; i += 1024) {
                int ixj = i ^ j;
                if (ixj > i) {
                    unsigned long long a = keys[i], b = keys[ixj];
                    bool desc = ((i & k) == 0);
                    if (desc ? (a < b) : (a > b)) { keys[i] = b; keys[ixj] = a; }
                }
            }
            __syncthreads();
        }
    }
    if (tid < KEEP_) {
        keepidx[(size_t)bh * KEEP_ + tid] = (N_ - 1) - (int)(keys[tid] & 0xffffffffu);
    }
}

// ---------------- gather: k hi/lo row-major, vT hi/lo transposed ------------
// block = (bh, 64-key chunk). Phase1: rows -> k_hi/k_lo + V into LDS.
// Phase2: LDS transpose -> vT_hi/vT_lo [bh][d][key].
__global__ __launch_bounds__(256) void gather_kernel(
    const float* __restrict__ qkv, const int* __restrict__ keepidx,
    unsigned short* __restrict__ k_hi, unsigned short* __restrict__ k_lo,
    unsigned short* __restrict__ vT_hi, unsigned short* __restrict__ vT_lo)
{
    __shared__ float vS[64][65];
    const int bh = blockIdx.x >> 4;
    const int chunk = blockIdx.x & 15;
    const int b = bh / H_, h = bh % H_;
    const int wave = threadIdx.x >> 6, lane = threadIdx.x & 63;
    const int j0 = chunk * 64;

#pragma unroll
    for (int jj = 0; jj < 16; ++jj) {
        int j = wave * 16 + jj;
        int n = keepidx[(size_t)bh * KEEP_ + j0 + j];
        size_t base = ((size_t)b * N_ + n) * (3 * C_) + (size_t)h * HD_ + lane;
        float kv = qkv[base + C_];
        float vv = qkv[base + 2 * C_];
        unsigned short kh = f2bf(kv);
        size_t ko = ((size_t)bh * KEEP_ + j0 + j) * HD_ + lane;
        k_hi[ko] = kh;
        k_lo[ko] = f2bf(kv - bf2f(kh));
        vS[j][lane] = vv;
    }
    __syncthreads();
#pragma unroll
    for (int dd = 0; dd < 16; ++dd) {
        int d = wave * 16 + dd;
        float vv = vS[lane][d];
        unsigned short vh = f2bf(vv);
        size_t vo = ((size_t)bh * HD_ + d) * KEEP_ + j0 + lane;
        vT_hi[vo] = vh;
        vT_lo[vo] = f2bf(vv - bf2f(vh));
    }
}

// ---------------- MFMA flash attention --------------------------------------
// block: (bh, 128 q-rows), 4 waves x 32 rows. K-tiles of 64 keys.
// 16x16x32 bf16 MFMA, 3-product hi/lo split for QK and PV.
__global__ __launch_bounds__(256, 2) void attn_kernel(
    const unsigned short* __restrict__ q_hi, const unsigned short* __restrict__ q_lo,
    const unsigned short* __restrict__ k_hi, const unsigned short* __restrict__ k_lo,
    const unsigned short* __restrict__ vT_hi, const unsigned short* __restrict__ vT_lo,
    float* __restrict__ attn_out)
{
    // XCD-chunked swizzle: nwg=768 = 8*96 (bijective)
    int bid = (blockIdx.x & 7) * 96 + (blockIdx.x >> 3);
    const int bh = bid >> 4;       // 16 q-tiles of 128 rows
    const int qt = bid & 15;
    const int b = bh / H_, h = bh - b * H_;
    const int wave = threadIdx.x >> 6;
    const int lane = threadIdx.x & 63;
    const int row16 = lane & 15;   // A-row / B-col / D-col
    const int grp = lane >> 4;     // k-chunk group / D-row group

    __shared__ unsigned short pHi[4][32][72];
    __shared__ unsigned short pLo[4][32][72];

    const int n0 = qt * 128 + wave * 32;

    // Q A-frags, persistent: [mt][ks], hi & lo
    short8v aQh[2][2], aQl[2][2];
#pragma unroll
    for (int mt = 0; mt < 2; ++mt)
#pragma unroll
        for (int ks = 0; ks < 2; ++ks) {
            size_t off = ((size_t)bh * N_ + n0 + mt * 16 + row16) * HD_ + ks * 32 + grp * 8;
            aQh[mt][ks] = *reinterpret_cast<const short8v*>(q_hi + off);
            aQl[mt][ks] = *reinterpret_cast<const short8v*>(q_lo + off);
        }

    f32x4 o[2][4];
    float m[2][4], s[2][4];
#pragma unroll
    for (int mt = 0; mt < 2; ++mt)
#pragma unroll
        for (int nt = 0; nt < 4; ++nt) o[mt][nt] = (f32x4)0.f;
#pragma unroll
    for (int mt = 0; mt < 2; ++mt)
#pragma unroll
        for (int r = 0; r < 4; ++r) { m[mt][r] = -1e30f; s[mt][r] = 0.f; }

    for (int t = 0; t < KEEP_ / 64; ++t) {
        // ---- S = Q K^T (3-product) ----
        f32x4 sv[2][4];
#pragma unroll
        for (int mt = 0; mt < 2; ++mt)
#pragma unroll
            for (int nt = 0; nt < 4; ++nt) sv[mt][nt] = (f32x4)0.f;

#pragma unroll
        for (int nt = 0; nt < 4; ++nt) {
            short8v bKh[2], bKl[2];
#pragma unroll
            for (int ks = 0; ks < 2; ++ks) {
                size_t koff = ((size_t)bh * KEEP_ + t * 64 + nt * 16 + row16) * HD_ + ks * 32 + grp * 8;
                bKh[ks] = *reinterpret_cast<const short8v*>(k_hi + koff);
                bKl[ks] = *reinterpret_cast<const short8v*>(k_lo + koff);
            }
#pragma unroll
            for (int mt = 0; mt < 2; ++mt)
#pragma unroll
                for (int ks = 0; ks < 2; ++ks) {
                    sv[mt][nt] = __builtin_amdgcn_mfma_f32_16x16x32_bf16(aQh[mt][ks], bKh[ks], sv[mt][nt], 0, 0, 0);
                    sv[mt][nt] = __builtin_amdgcn_mfma_f32_16x16x32_bf16(aQh[mt][ks], bKl[ks], sv[mt][nt], 0, 0, 0);
                    sv[mt][nt] = __builtin_amdgcn_mfma_f32_16x16x32_bf16(aQl[mt][ks], bKh[ks], sv[mt][nt], 0, 0, 0);
                }
        }

        // ---- online softmax (per wave, rows = grp*4+r) ----
#pragma unroll
        for (int mt = 0; mt < 2; ++mt) {
            float lv[4][4];
            float mx[4] = {-1e30f, -1e30f, -1e30f, -1e30f};
#pragma unroll
            for (int nt = 0; nt < 4; ++nt)
#pragma unroll
                for (int r = 0; r < 4; ++r) {
                    float x = fminf(fmaxf(sv[mt][nt][r] * 0.125f, -50.f), 50.f);
                    lv[nt][r] = x;
                    mx[r] = fmaxf(mx[r], x);
                }
#pragma unroll
            for (int off = 1; off < 16; off <<= 1)
#pragma unroll
                for (int r = 0; r < 4; ++r) mx[r] = fmaxf(mx[r], __shfl_xor(mx[r], off));
            float mn[4], c[4], ps[4];
#pragma unroll
            for (int r = 0; r < 4; ++r) {
                mn[r] = fmaxf(m[mt][r], mx[r]);
                c[r] = __expf(m[mt][r] - mn[r]);
                m[mt][r] = mn[r];
                ps[r] = 0.f;
            }
#pragma unroll
            for (int nt = 0; nt < 4; ++nt)
#pragma unroll
                for (int r = 0; r < 4; ++r) {
                    float p = __expf(lv[nt][r] - mn[r]);
                    ps[r] += p;
                    unsigned short ph = f2bf(p);
                    pHi[wave][mt * 16 + grp * 4 + r][nt * 16 + row16] = ph;
                    pLo[wave][mt * 16 + grp * 4 + r][nt * 16 + row16] = f2bf(p - bf2f(ph));
                }
#pragma unroll
            for (int off = 1; off < 16; off <<= 1)
#pragma unroll
                for (int r = 0; r < 4; ++r) ps[r] += __shfl_xor(ps[r], off);
#pragma unroll
            for (int r = 0; r < 4; ++r) s[mt][r] = s[mt][r] * c[r] + ps[r];
#pragma unroll
            for (int nt = 0; nt < 4; ++nt)
#pragma unroll
                for (int r = 0; r < 4; ++r) o[mt][nt][r] *= c[r];
        }

        // ---- O += P V (3-product); P via per-wave LDS round-trip ----
#pragma unroll
        for (int nt = 0; nt < 4; ++nt) {
            short8v bVh[2], bVl[2];
#pragma unroll
            for (int ks = 0; ks < 2; ++ks) {
                size_t voff = ((size_t)bh * HD_ + nt * 16 + row16) * KEEP_ + t * 64 + ks * 32 + grp * 8;
                bVh[ks] = *reinterpret_cast<const short8v*>(vT_hi + voff);
                bVl[ks] = *reinterpret_cast<const short8v*>(vT_lo + voff);
            }
#pragma unroll
            for (int mt = 0; mt < 2; ++mt)
#pragma unroll
                for (int ks = 0; ks < 2; ++ks) {
                    short8v aPh = *reinterpret_cast<const short8v*>(&pHi[wave][mt * 16 + row16][ks * 32 + grp * 8]);
                    short8v aPl = *reinterpret_cast<const short8v*>(&pLo[wave][mt * 16 + row16][ks * 32 + grp * 8]);
                    o[mt][nt] = __builtin_amdgcn_mfma_f32_16x16x32_bf16(aPh, bVh[ks], o[mt][nt], 0, 0, 0);
                    o[mt][nt] = __builtin_amdgcn_mfma_f32_16x16x32_bf16(aPh, bVl[ks], o[mt][nt], 0, 0, 0);
                    o[mt][nt] = __builtin_amdgcn_mfma_f32_16x16x32_bf16(aPl, bVh[ks], o[mt][nt], 0, 0, 0);
                }
        }
    }

    // ---- epilogue: normalize + write attn_out[b][n][h][d] ----
#pragma unroll
    for (int mt = 0; mt < 2; ++mt)
#pragma unroll
        for (int nt = 0; nt < 4; ++nt)
#pragma unroll
            for (int r = 0; r < 4; ++r) {
                int n = n0 + mt * 16 + grp * 4 + r;
                int d = nt * 16 + row16;
                attn_out[((size_t)b * N_ + n) * C_ + (size_t)h * HD_ + d] = o[mt][nt][r] / s[mt][r];
            }
}

// ---------------------------------------------------------------------------
extern "C" void kernel_launch(void* const* d_in, const int* in_sizes, int n_in,
                              void* d_out, int out_size, void* d_ws, size_t ws_size,
                              hipStream_t stream)
{
    const float* x      = (const float*)d_in[0];
    const float* w_qkv  = (const float*)d_in[1];
    const float* w_proj = (const float*)d_in[2];
    const float* b_proj = (const float*)d_in[3];
    float* out = (float*)d_out;

    char* cur = (char*)d_ws;
    float* qkv = (float*)cur;              cur += (size_t)B_ * N_ * 3 * C_ * 4;       // 75.5 MB
    float* scores = (float*)cur;           cur += (size_t)BH_ * N_ * 4;               // 0.4 MB
    int* keepidx = (int*)cur;              cur += (size_t)BH_ * KEEP_ * 4;            // 0.2 MB
    unsigned short* q_hi = (unsigned short*)cur;  cur += (size_t)BH_ * N_ * HD_ * 2;  // 12.6 MB
    unsigned short* q_lo = (unsigned short*)cur;  cur += (size_t)BH_ * N_ * HD_ * 2;
    unsigned short* k_hi = (unsigned short*)cur;  cur += (size_t)BH_ * KEEP_ * HD_ * 2;
    unsigned short* k_lo = (unsigned short*)cur;  cur += (size_t)BH_ * KEEP_ * HD_ * 2;
    unsigned short* vT_hi = (unsigned short*)cur; cur += (size_t)BH_ * HD_ * KEEP_ * 2;
    unsigned short* vT_lo = (unsigned short*)cur; cur += (size_t)BH_ * HD_ * KEEP_ * 2;
    float* attn_o = qkv;  // qkv is dead after gather; alias (25.2 MB < 75.5 MB)

    // 1) qkv = x @ w_qkv    [8192 x 2304]
    {
        dim3 grid((3 * C_) / 64, (B_ * N_) / 64);
        sgemm64<false><<<grid, 256, 0, stream>>>(x, w_qkv, qkv, B_ * N_, 3 * C_, C_, nullptr);
    }
    // 2) scores + q hi/lo
    score_kernel<<<(BH_ * N_) / 4, 256, 0, stream>>>(qkv, scores, q_hi, q_lo);
    // 3) top-k
    topk_kernel<<<BH_, 1024, 0, stream>>>(scores, keepidx);
    // 4) gather k hi/lo + vT hi/lo
    gather_kernel<<<BH_ * (KEEP_ / 64), 256, 0, stream>>>(qkv, keepidx, k_hi, k_lo, vT_hi, vT_lo);
    // 5) MFMA attention (writes attn_o, aliasing qkv)
    attn_kernel<<<BH_ * (N_ / 128), 256, 0, stream>>>(q_hi, q_lo, k_hi, k_lo, vT_hi, vT_lo, attn_o);
    // 6) out = clip(attn_o @ w_proj + b, -10, 10)
    {
        dim3 grid(C_ / 64, (B_ * N_) / 64);
        sgemm64<true><<<grid, 256, 0, stream>>>(attn_o, w_proj, out, B_ * N_, C_, C_, b_proj);
    }
}

// Round 4
// 448.340 us; speedup vs baseline: 3.1900x; 1.9092x over previous
//
#include <hip/hip_runtime.h>
#include <hip/hip_bf16.h>
#include <math.h>

// ---------------------------------------------------------------------------
// BiFormerAttention: B=4, N=2048, C=768, H=12, hd=64, keep=1024
// GEMMs on MFMA f16 with 3-product hi/lo split (fp32-grade: 11+11 mantissa
// bits, dropped lo*lo term <= 2^-24 -> top-k selection set preserved).
// Attention on MFMA bf16 3-product split (downstream of selection).
// ---------------------------------------------------------------------------

#define B_  4
#define N_  2048
#define C_  768
#define H_  12
#define HD_ 64
#define KEEP_ 1024
#define BH_ (B_ * H_)
#define GK  768   // K dim of both big GEMMs

typedef __attribute__((ext_vector_type(8))) short short8v;     // 8 bf16
typedef __attribute__((ext_vector_type(4))) float f32x4;       // MFMA C/D
typedef __attribute__((ext_vector_type(8))) _Float16 f16x8;    // 8 fp16
typedef __attribute__((ext_vector_type(4))) _Float16 f16x4;

__device__ inline unsigned short f2bf(float f) {               // RNE f32->bf16
    unsigned u = __float_as_uint(f);
    unsigned r = (u + 0x7fffu + ((u >> 16) & 1u)) >> 16;
    return (unsigned short)r;
}
__device__ inline float bf2f(unsigned short h) {
    return __uint_as_float(((unsigned)h) << 16);
}

__device__ inline void gload16(const _Float16* g, const _Float16* l) {
    __builtin_amdgcn_global_load_lds(
        (const __attribute__((address_space(1))) unsigned int*)(g),
        (__attribute__((address_space(3))) unsigned int*)(l), 16, 0, 0);
}

// ---------------- elementwise split: fp32 -> f16 hi + f16 lo ----------------
__global__ __launch_bounds__(256) void split4_kernel(
    const float* __restrict__ in, _Float16* __restrict__ hi,
    _Float16* __restrict__ lo, int n4)
{
    int i = blockIdx.x * 256 + threadIdx.x;
    if (i >= n4) return;
    float4 v = reinterpret_cast<const float4*>(in)[i];
    f16x4 h, l;
    h[0] = (_Float16)v.x; l[0] = (_Float16)(v.x - (float)h[0]);
    h[1] = (_Float16)v.y; l[1] = (_Float16)(v.y - (float)h[1]);
    h[2] = (_Float16)v.z; l[2] = (_Float16)(v.z - (float)h[2]);
    h[3] = (_Float16)v.w; l[3] = (_Float16)(v.w - (float)h[3]);
    reinterpret_cast<f16x4*>(hi)[i] = h;
    reinterpret_cast<f16x4*>(lo)[i] = l;
}

// ---------------- transpose + split: W[K][N] fp32 -> T[N][GK] f16 hi/lo -----
__global__ __launch_bounds__(256) void tsplit_kernel(
    const float* __restrict__ W, _Float16* __restrict__ Th,
    _Float16* __restrict__ Tl, int N)
{
    __shared__ float t[32][33];
    int n0 = blockIdx.x * 32, k0 = blockIdx.y * 32;
    int r = threadIdx.x >> 3, c4 = (threadIdx.x & 7) << 2;
    float4 v = *reinterpret_cast<const float4*>(&W[(size_t)(k0 + r) * N + n0 + c4]);
    t[r][c4 + 0] = v.x; t[r][c4 + 1] = v.y; t[r][c4 + 2] = v.z; t[r][c4 + 3] = v.w;
    __syncthreads();
#pragma unroll
    for (int j = 0; j < 4; ++j) {
        float val = t[c4 + j][r];                 // = W[k0+c4+j][n0+r]
        _Float16 h = (_Float16)val;
        size_t o = (size_t)(n0 + r) * GK + k0 + c4 + j;
        Th[o] = h;
        Tl[o] = (_Float16)(val - (float)h);
    }
}

// ---------------- MFMA split-f16 GEMM: C[M][N] = A[M][GK] * B^T[N][GK] ------
// 128x128 tile, BK=64, 4 waves x (64x64), 16x16x32 f16, 3-product split.
// LDS tiles linear [128][64] f16; T2 XOR swizzle (chunk ^= row&7) applied on
// the global SOURCE address at staging and on the ds_read side (rule 21).
template <bool EPI>
__global__ __launch_bounds__(256, 2) void mfma_gemm(
    const _Float16* __restrict__ Ah, const _Float16* __restrict__ Al,
    const _Float16* __restrict__ Bh, const _Float16* __restrict__ Bl,
    float* __restrict__ C, int N, const float* __restrict__ bias,
    int gx, int cpx)
{
    __shared__ _Float16 lds[4][128 * 64];   // Ah,Al,Bh,Bl tiles (64 KiB)

    const int sb = ((int)blockIdx.x & 7) * cpx + ((int)blockIdx.x >> 3);
    const int bx = sb % gx, by = sb / gx;
    const int row0 = by * 128, col0 = bx * 128;

    const int tid = threadIdx.x;
    const int wave = tid >> 6, lane = tid & 63;
    const int fr = lane & 15, grp = lane >> 4;
    const int wr = wave >> 1, wc = wave & 1;

    // staging decomposition: per issue, 8 rows x 128B; lane -> (dr, chunk)
    const int dr = lane >> 3, ch = lane & 7;
    const int sc = (ch ^ dr) * 8;           // pre-swizzled source chunk (f16 elems)

    const _Float16* srcs[4] = {
        Ah + (size_t)row0 * GK, Al + (size_t)row0 * GK,
        Bh + (size_t)col0 * GK, Bl + (size_t)col0 * GK };

    f32x4 acc[4][4];
#pragma unroll
    for (int mt = 0; mt < 4; ++mt)
#pragma unroll
        for (int nt = 0; nt < 4; ++nt) acc[mt][nt] = (f32x4)0.f;

    const int swz0 = ((0 + grp) ^ (fr & 7)) * 16;   // ks=0 read chunk (bytes)
    const int swz1 = ((4 + grp) ^ (fr & 7)) * 16;   // ks=1

    for (int k0 = 0; k0 < GK; k0 += 64) {
        __syncthreads();                    // previous compute done, LDS free
#pragma unroll
        for (int t = 0; t < 4; ++t) {
            const _Float16* gsrc = srcs[t] + k0 + sc;
#pragma unroll
            for (int i = 0; i < 4; ++i) {
                int rb = wave * 32 + i * 8;
                gload16(gsrc + (size_t)(rb + dr) * GK, &lds[t][rb * 64]);
            }
        }
        __syncthreads();                    // vmcnt drained before barrier

        f16x8 fa[4][2][2];                  // [mt][ks][hi/lo]
#pragma unroll
        for (int mt = 0; mt < 4; ++mt) {
            int rbyte = (wr * 64 + mt * 16 + fr) * 128;
            fa[mt][0][0] = *(const f16x8*)((const char*)lds[0] + rbyte + swz0);
            fa[mt][1][0] = *(const f16x8*)((const char*)lds[0] + rbyte + swz1);
            fa[mt][0][1] = *(const f16x8*)((const char*)lds[1] + rbyte + swz0);
            fa[mt][1][1] = *(const f16x8*)((const char*)lds[1] + rbyte + swz1);
        }
#pragma unroll
        for (int nt = 0; nt < 4; ++nt) {
            int rbyte = (wc * 64 + nt * 16 + fr) * 128;
            f16x8 bh0 = *(const f16x8*)((const char*)lds[2] + rbyte + swz0);
            f16x8 bh1 = *(const f16x8*)((const char*)lds[2] + rbyte + swz1);
            f16x8 bl0 = *(const f16x8*)((const char*)lds[3] + rbyte + swz0);
            f16x8 bl1 = *(const f16x8*)((const char*)lds[3] + rbyte + swz1);
#pragma unroll
            for (int mt = 0; mt < 4; ++mt) {
                acc[mt][nt] = __builtin_amdgcn_mfma_f32_16x16x32_f16(fa[mt][0][0], bh0, acc[mt][nt], 0, 0, 0);
                acc[mt][nt] = __builtin_amdgcn_mfma_f32_16x16x32_f16(fa[mt][0][0], bl0, acc[mt][nt], 0, 0, 0);
                acc[mt][nt] = __builtin_amdgcn_mfma_f32_16x16x32_f16(fa[mt][0][1], bh0, acc[mt][nt], 0, 0, 0);
                acc[mt][nt] = __builtin_amdgcn_mfma_f32_16x16x32_f16(fa[mt][1][0], bh1, acc[mt][nt], 0, 0, 0);
                acc[mt][nt] = __builtin_amdgcn_mfma_f32_16x16x32_f16(fa[mt][1][0], bl1, acc[mt][nt], 0, 0, 0);
                acc[mt][nt] = __builtin_amdgcn_mfma_f32_16x16x32_f16(fa[mt][1][1], bh1, acc[mt][nt], 0, 0, 0);
            }
        }
    }

    // epilogue: D col=lane&15 (N dim), row=grp*4+reg (M dim)  [R2-verified]
#pragma unroll
    for (int mt = 0; mt < 4; ++mt)
#pragma unroll
        for (int nt = 0; nt < 4; ++nt) {
            int col = col0 + wc * 64 + nt * 16 + fr;
            float bv = 0.f;
            if (EPI) bv = bias[col];
#pragma unroll
            for (int r = 0; r < 4; ++r) {
                int row = row0 + wr * 64 + mt * 16 + grp * 4 + r;
                float v = acc[mt][nt][r];
                if (EPI) v = fminf(fmaxf(v + bv, -10.f), 10.f);
                C[(size_t)row * N + col] = v;
            }
        }
}

// ---------------- scores = sum(q^2); also emit q hi/lo bf16 -----------------
__global__ __launch_bounds__(256) void score_kernel(
    const float* __restrict__ qkv, float* __restrict__ scores,
    unsigned short* __restrict__ q_hi, unsigned short* __restrict__ q_lo)
{
    int w = blockIdx.x * 4 + (threadIdx.x >> 6);
    int lane = threadIdx.x & 63;
    int bh = w >> 11;
    int n = w & (N_ - 1);
    int b = bh / H_, h = bh % H_;
    float q = qkv[((size_t)b * N_ + n) * (3 * C_) + (size_t)h * HD_ + lane];
    unsigned short qh = f2bf(q);
    size_t qo = ((size_t)bh * N_ + n) * HD_ + lane;
    q_hi[qo] = qh;
    q_lo[qo] = f2bf(q - bf2f(qh));
    float ss = q * q;
#pragma unroll
    for (int off = 32; off; off >>= 1) ss += __shfl_xor(ss, off);
    if (lane == 0) scores[(size_t)bh * N_ + n] = ss;
}

// ---------------- top-1024 of 2048 per (b,h): bitonic sort ------------------
__global__ __launch_bounds__(1024) void topk_kernel(
    const float* __restrict__ scores, int* __restrict__ keepidx)
{
    __shared__ unsigned long long keys[N_];
    const int bh = blockIdx.x;
    const int tid = threadIdx.x;
    const float* sc = scores + (size_t)bh * N_;
    for (int i = tid; i < N_; i += 1024) {
        unsigned fb = __float_as_uint(sc[i]);
        keys[i] = ((unsigned long long)fb << 32) | (unsigned)(N_ - 1 - i);
    }
    __syncthreads();
    for (int k = 2; k <= N_; k <<= 1) {
        for (int j = k >> 1; j > 0; j >>= 1) {
            for (int i = tid; i < N_; i += 1024) {
                int ixj = i ^ j;
                if (ixj > i) {
                    unsigned long long a = keys[i], b = keys[ixj];
                    bool desc = ((i & k) == 0);
                    if (desc ? (a < b) : (a > b)) { keys[i] = b; keys[ixj] = a; }
                }
            }
            __syncthreads();
        }
    }
    if (tid < KEEP_) {
        keepidx[(size_t)bh * KEEP_ + tid] = (N_ - 1) - (int)(keys[tid] & 0xffffffffu);
    }
}

// ---------------- gather: k hi/lo row-major, vT hi/lo transposed ------------
__global__ __launch_bounds__(256) void gather_kernel(
    const float* __restrict__ qkv, const int* __restrict__ keepidx,
    unsigned short* __restrict__ k_hi, unsigned short* __restrict__ k_lo,
    unsigned short* __restrict__ vT_hi, unsigned short* __restrict__ vT_lo)
{
    __shared__ float vS[64][65];
    const int bh = blockIdx.x >> 4;
    const int chunk = blockIdx.x & 15;
    const int b = bh / H_, h = bh % H_;
    const int wave = threadIdx.x >> 6, lane = threadIdx.x & 63;
    const int j0 = chunk * 64;

#pragma unroll
    for (int jj = 0; jj < 16; ++jj) {
        int j = wave * 16 + jj;
        int n = keepidx[(size_t)bh * KEEP_ + j0 + j];
        size_t base = ((size_t)b * N_ + n) * (3 * C_) + (size_t)h * HD_ + lane;
        float kv = qkv[base + C_];
        float vv = qkv[base + 2 * C_];
        unsigned short kh = f2bf(kv);
        size_t ko = ((size_t)bh * KEEP_ + j0 + j) * HD_ + lane;
        k_hi[ko] = kh;
        k_lo[ko] = f2bf(kv - bf2f(kh));
        vS[j][lane] = vv;
    }
    __syncthreads();
#pragma unroll
    for (int dd = 0; dd < 16; ++dd) {
        int d = wave * 16 + dd;
        float vv = vS[lane][d];
        unsigned short vh = f2bf(vv);
        size_t vo = ((size_t)bh * HD_ + d) * KEEP_ + j0 + lane;
        vT_hi[vo] = vh;
        vT_lo[vo] = f2bf(vv - bf2f(vh));
    }
}

// ---------------- MFMA flash attention --------------------------------------
__global__ __launch_bounds__(256, 2) void attn_kernel(
    const unsigned short* __restrict__ q_hi, const unsigned short* __restrict__ q_lo,
    const unsigned short* __restrict__ k_hi, const unsigned short* __restrict__ k_lo,
    const unsigned short* __restrict__ vT_hi, const unsigned short* __restrict__ vT_lo,
    float* __restrict__ attn_out)
{
    int bid = (blockIdx.x & 7) * 96 + (blockIdx.x >> 3);
    const int bh = bid >> 4;
    const int qt = bid & 15;
    const int b = bh / H_, h = bh - b * H_;
    const int wave = threadIdx.x >> 6;
    const int lane = threadIdx.x & 63;
    const int row16 = lane & 15;
    const int grp = lane >> 4;

    __shared__ unsigned short pHi[4][32][72];
    __shared__ unsigned short pLo[4][32][72];

    const int n0 = qt * 128 + wave * 32;

    short8v aQh[2][2], aQl[2][2];
#pragma unroll
    for (int mt = 0; mt < 2; ++mt)
#pragma unroll
        for (int ks = 0; ks < 2; ++ks) {
            size_t off = ((size_t)bh * N_ + n0 + mt * 16 + row16) * HD_ + ks * 32 + grp * 8;
            aQh[mt][ks] = *reinterpret_cast<const short8v*>(q_hi + off);
            aQl[mt][ks] = *reinterpret_cast<const short8v*>(q_lo + off);
        }

    f32x4 o[2][4];
    float m[2][4], s[2][4];
#pragma unroll
    for (int mt = 0; mt < 2; ++mt)
#pragma unroll
        for (int nt = 0; nt < 4; ++nt) o[mt][nt] = (f32x4)0.f;
#pragma unroll
    for (int mt = 0; mt < 2; ++mt)
#pragma unroll
        for (int r = 0; r < 4; ++r) { m[mt][r] = -1e30f; s[mt][r] = 0.f; }

    for (int t = 0; t < KEEP_ / 64; ++t) {
        f32x4 sv[2][4];
#pragma unroll
        for (int mt = 0; mt < 2; ++mt)
#pragma unroll
            for (int nt = 0; nt < 4; ++nt) sv[mt][nt] = (f32x4)0.f;

#pragma unroll
        for (int nt = 0; nt < 4; ++nt) {
            short8v bKh[2], bKl[2];
#pragma unroll
            for (int ks = 0; ks < 2; ++ks) {
                size_t koff = ((size_t)bh * KEEP_ + t * 64 + nt * 16 + row16) * HD_ + ks * 32 + grp * 8;
                bKh[ks] = *reinterpret_cast<const short8v*>(k_hi + koff);
                bKl[ks] = *reinterpret_cast<const short8v*>(k_lo + koff);
            }
#pragma unroll
            for (int mt = 0; mt < 2; ++mt)
#pragma unroll
                for (int ks = 0; ks < 2; ++ks) {
                    sv[mt][nt] = __builtin_amdgcn_mfma_f32_16x16x32_bf16(aQh[mt][ks], bKh[ks], sv[mt][nt], 0, 0, 0);
                    sv[mt][nt] = __builtin_amdgcn_mfma_f32_16x16x32_bf16(aQh[mt][ks], bKl[ks], sv[mt][nt], 0, 0, 0);
                    sv[mt][nt] = __builtin_amdgcn_mfma_f32_16x16x32_bf16(aQl[mt][ks], bKh[ks], sv[mt][nt], 0, 0, 0);
                }
        }

#pragma unroll
        for (int mt = 0; mt < 2; ++mt) {
            float lv[4][4];
            float mx[4] = {-1e30f, -1e30f, -1e30f, -1e30f};
#pragma unroll
            for (int nt = 0; nt < 4; ++nt)
#pragma unroll
                for (int r = 0; r < 4; ++r) {
                    float x = fminf(fmaxf(sv[mt][nt][r] * 0.125f, -50.f), 50.f);
                    lv[nt][r] = x;
                    mx[r] = fmaxf(mx[r], x);
                }
#pragma unroll
            for (int off = 1; off < 16; off <<= 1)
#pragma unroll
                for (int r = 0; r < 4; ++r) mx[r] = fmaxf(mx[r], __shfl_xor(mx[r], off));
            float mn[4], c[4], ps[4];
#pragma unroll
            for (int r = 0; r < 4; ++r) {
                mn[r] = fmaxf(m[mt][r], mx[r]);
                c[r] = __expf(m[mt][r] - mn[r]);
                m[mt][r] = mn[r];
                ps[r] = 0.f;
            }
#pragma unroll
            for (int nt = 0; nt < 4; ++nt)
#pragma unroll
                for (int r = 0; r < 4; ++r) {
                    float p = __expf(lv[nt][r] - mn[r]);
                    ps[r] += p;
                    unsigned short ph = f2bf(p);
                    pHi[wave][mt * 16 + grp * 4 + r][nt * 16 + row16] = ph;
                    pLo[wave][mt * 16 + grp * 4 + r][nt * 16 + row16] = f2bf(p - bf2f(ph));
                }
#pragma unroll
            for (int off = 1; off < 16; off <<= 1)
#pragma unroll
                for (int r = 0; r < 4; ++r) ps[r] += __shfl_xor(ps[r], off);
#pragma unroll
            for (int r = 0; r < 4; ++r) s[mt][r] = s[mt][r] * c[r] + ps[r];
#pragma unroll
            for (int nt = 0; nt < 4; ++nt)
#pragma unroll
                for (int r = 0; r < 4; ++r) o[mt][nt][r] *= c[r];
        }

#pragma unroll
        for (int nt = 0; nt < 4; ++nt) {
            short8v bVh[2], bVl[2];
#pragma unroll
            for (int ks = 0; ks < 2; ++ks) {
                size_t voff = ((size_t)bh * HD_ + nt * 16 + row16) * KEEP_ + t * 64 + ks * 32 + grp * 8;
                bVh[ks] = *reinterpret_cast<const short8v*>(vT_hi + voff);
                bVl[ks] = *reinterpret_cast<const short8v*>(vT_lo + voff);
            }
#pragma unroll
            for (int mt = 0; mt < 2; ++mt)
#pragma unroll
                for (int ks = 0; ks < 2; ++ks) {
                    short8v aPh = *reinterpret_cast<const short8v*>(&pHi[wave][mt * 16 + row16][ks * 32 + grp * 8]);
                    short8v aPl = *reinterpret_cast<const short8v*>(&pLo[wave][mt * 16 + row16][ks * 32 + grp * 8]);
                    o[mt][nt] = __builtin_amdgcn_mfma_f32_16x16x32_bf16(aPh, bVh[ks], o[mt][nt], 0, 0, 0);
                    o[mt][nt] = __builtin_amdgcn_mfma_f32_16x16x32_bf16(aPh, bVl[ks], o[mt][nt], 0, 0, 0);
                    o[mt][nt] = __builtin_amdgcn_mfma_f32_16x16x32_bf16(aPl, bVh[ks], o[mt][nt], 0, 0, 0);
                }
        }
    }

#pragma unroll
    for (int mt = 0; mt < 2; ++mt)
#pragma unroll
        for (int nt = 0; nt < 4; ++nt)
#pragma unroll
            for (int r = 0; r < 4; ++r) {
                int n = n0 + mt * 16 + grp * 4 + r;
                int d = nt * 16 + row16;
                attn_out[((size_t)b * N_ + n) * C_ + (size_t)h * HD_ + d] = o[mt][nt][r] / s[mt][r];
            }
}

// ---------------------------------------------------------------------------
extern "C" void kernel_launch(void* const* d_in, const int* in_sizes, int n_in,
                              void* d_out, int out_size, void* d_ws, size_t ws_size,
                              hipStream_t stream)
{
    const float* x      = (const float*)d_in[0];
    const float* w_qkv  = (const float*)d_in[1];
    const float* w_proj = (const float*)d_in[2];
    const float* b_proj = (const float*)d_in[3];
    float* out = (float*)d_out;

    char* cur = (char*)d_ws;
    float* qkv = (float*)cur;              cur += (size_t)B_ * N_ * 3 * C_ * 4;       // 75.5 MB
    float* scores = (float*)cur;           cur += (size_t)BH_ * N_ * 4;
    int* keepidx = (int*)cur;              cur += (size_t)BH_ * KEEP_ * 4;
    // 25.2 MB region with 3 sequential lifetimes: xh/xl -> q_hi/q_lo -> aoh/aol
    char* shared25 = cur;                  cur += (size_t)BH_ * N_ * HD_ * 2 * 2;
    unsigned short* k_hi = (unsigned short*)cur;  cur += (size_t)BH_ * KEEP_ * HD_ * 2;
    unsigned short* k_lo = (unsigned short*)cur;  cur += (size_t)BH_ * KEEP_ * HD_ * 2;
    unsigned short* vT_hi = (unsigned short*)cur; cur += (size_t)BH_ * HD_ * KEEP_ * 2;
    unsigned short* vT_lo = (unsigned short*)cur; cur += (size_t)BH_ * HD_ * KEEP_ * 2;
    _Float16* wTh = (_Float16*)cur;        cur += (size_t)(3 * C_) * GK * 2;          // 7.1 MB
    _Float16* wTl = (_Float16*)cur;        cur += (size_t)(3 * C_) * GK * 2;

    _Float16* xh = (_Float16*)shared25;
    _Float16* xl = xh + (size_t)B_ * N_ * C_;
    unsigned short* q_hi = (unsigned short*)shared25;
    unsigned short* q_lo = q_hi + (size_t)BH_ * N_ * HD_;
    _Float16* aoh = (_Float16*)shared25;
    _Float16* aol = aoh + (size_t)B_ * N_ * C_;
    float* attn_o = qkv;   // qkv dead after gather

    const int n4x = (B_ * N_ * C_) / 4;   // 1572864

    // 1) split x; transpose+split w_qkv; qkv = x @ w_qkv (MFMA split-f16)
    split4_kernel<<<n4x / 256, 256, 0, stream>>>(x, xh, xl, n4x);
    tsplit_kernel<<<dim3((3 * C_) / 32, GK / 32), 256, 0, stream>>>(w_qkv, wTh, wTl, 3 * C_);
    mfma_gemm<false><<<(B_ * N_ / 128) * (3 * C_ / 128), 256, 0, stream>>>(
        xh, xl, wTh, wTl, qkv, 3 * C_, nullptr, (3 * C_) / 128, (B_ * N_ / 128) * (3 * C_ / 128) / 8);
    // 2) scores + q hi/lo (overwrites xh/xl region — x is dead)
    score_kernel<<<(BH_ * N_) / 4, 256, 0, stream>>>(qkv, scores, q_hi, q_lo);
    // 3) top-k
    topk_kernel<<<BH_, 1024, 0, stream>>>(scores, keepidx);
    // 4) gather k hi/lo + vT hi/lo
    gather_kernel<<<BH_ * (KEEP_ / 64), 256, 0, stream>>>(qkv, keepidx, k_hi, k_lo, vT_hi, vT_lo);
    // 5) MFMA attention (writes attn_o, aliasing qkv)
    attn_kernel<<<BH_ * (N_ / 128), 256, 0, stream>>>(q_hi, q_lo, k_hi, k_lo, vT_hi, vT_lo, attn_o);
    // 6) split attn_o (overwrites q_hi/q_lo — dead); transpose+split w_proj;
    //    out = clip(attn_o @ w_proj + b, -10, 10)
    split4_kernel<<<n4x / 256, 256, 0, stream>>>(attn_o, aoh, aol, n4x);
    tsplit_kernel<<<dim3(C_ / 32, GK / 32), 256, 0, stream>>>(w_proj, wTh, wTl, C_);
    mfma_gemm<true><<<(B_ * N_ / 128) * (C_ / 128), 256, 0, stream>>>(
        aoh, aol, wTh, wTl, out, C_, b_proj, C_ / 128, (B_ * N_ / 128) * (C_ / 128) / 8);
}